// Round 6
// baseline (226.799 us; speedup 1.0000x reference)
//
#include <hip/hip_runtime.h>
#include <hip/hip_bf16.h>

// B=4, S=2048, D=1024, DH=64. Inputs/outputs are FLOAT32 (per reference).
typedef short bf16x8 __attribute__((ext_vector_type(8)));
typedef float f32x4  __attribute__((ext_vector_type(4)));
typedef _Float16 f16x8 __attribute__((ext_vector_type(8)));

#define MFMA16(a,b,c)  __builtin_amdgcn_mfma_f32_16x16x32_bf16((a),(b),(c),0,0,0)
#define MFMAF16(a,b,c) __builtin_amdgcn_mfma_f32_16x16x32_f16((a),(b),(c),0,0,0)

// async global->LDS: 16B per lane, lane i lands at lds_base + i*16
#define GLDS16(g,l) __builtin_amdgcn_global_load_lds( \
    (const __attribute__((address_space(1))) void*)(g), \
    (__attribute__((address_space(3))) void*)(l), 16, 0, 0)

__device__ __forceinline__ short f2bf(float f){
  union { float f; unsigned u; } v; v.f = f;
  unsigned r = v.u + 0x7fffu + ((v.u >> 16) & 1u);
  return (short)(r >> 16);
}
__device__ __forceinline__ float bf2f(short h){
  union { unsigned u; float f; } v; v.u = ((unsigned)(unsigned short)h) << 16;
  return v.f;
}
__device__ __forceinline__ void split8v(f32x4 a, f32x4 b, bf16x8& h, bf16x8& l){
  float t[8] = {a[0],a[1],a[2],a[3],b[0],b[1],b[2],b[3]};
  #pragma unroll
  for (int e = 0; e < 8; ++e){
    short hs = f2bf(t[e]);
    h[e] = hs;
    l[e] = f2bf(t[e] - bf2f(hs));
  }
}

// ---------------- P0a: transpose+split 6 weights (1024x64 f32 -> 64x1024 bf16 hi/lo) ----------------
__global__ void k_wt(const float* w0, const float* w1, const float* w2,
                     const float* w3, const float* w4, const float* w5,
                     unsigned short* __restrict__ wth, unsigned short* __restrict__ wtl){
  int p = blockIdx.y;
  const float* wp = p==0?w0:p==1?w1:p==2?w2:p==3?w3:p==4?w4:w5;
  int idx = blockIdx.x*256 + threadIdx.x;     // [0,65536)
  int n = idx >> 10, k = idx & 1023;
  float v = wp[k*64 + n];
  short hs = f2bf(v);
  wth[(size_t)p*65536 + n*1024 + k] = (unsigned short)hs;
  wtl[(size_t)p*65536 + n*1024 + k] = (unsigned short)f2bf(v - bf2f(hs));
}

// ---------------- P0b: x f32 -> xh/xl bf16 (once) ----------------
__global__ void k_xsplit(const float* __restrict__ x,
                         unsigned short* __restrict__ xh, unsigned short* __restrict__ xl){
  size_t i = ((size_t)blockIdx.x*256 + threadIdx.x)*8;
  f32x4 a = *(const f32x4*)(x + i);
  f32x4 b = *(const f32x4*)(x + i + 4);
  bf16x8 h, l;
  split8v(a, b, h, l);
  *(bf16x8*)(xh + i) = h;
  *(bf16x8*)(xl + i) = l;
}

// ---------------- P1: projections, 2 p's per block, DMA-staged ----------------
// f32 kept for p==2 (Vu, slot 0) and p==5 (Vc, slot 1); bf16 h/l for p 0..4.
__global__ __launch_bounds__(256) void k_proj(
    const unsigned short* __restrict__ xh, const unsigned short* __restrict__ xl,
    const unsigned short* __restrict__ wth, const unsigned short* __restrict__ wtl,
    float* __restrict__ proj,
    unsigned short* __restrict__ projh, unsigned short* __restrict__ projl){
  __shared__ __align__(16) char sm[49152];  // xh 8K | xl 8K | w0h 8K | w0l 8K | w1h 8K | w1l 8K
  int blk = blockIdx.x;
  int rb = blk/3, pg = blk - rb*3;
  int tid = threadIdx.x, w = tid >> 6, lane = tid & 63;
  int lm = lane & 15, quad = lane >> 4;
  int srow = lane >> 3, scg = (lane & 7) ^ srow;
  const char* xhg = (const char*)xh;
  const char* xlg = (const char*)xl;
  const char* w0h = (const char*)wth + (size_t)(pg*2  )*131072;
  const char* w0l = (const char*)wtl + (size_t)(pg*2  )*131072;
  const char* w1h = (const char*)wth + (size_t)(pg*2+1)*131072;
  const char* w1l = (const char*)wtl + (size_t)(pg*2+1)*131072;
  f32x4 acc[2][4] = {};
  for (int k0 = 0; k0 < 1024; k0 += 64){
    __syncthreads();
    size_t cb = (size_t)k0*2 + scg*16;
    #pragma unroll
    for (int i2 = 0; i2 < 2; ++i2){
      int i = w*2 + i2;
      size_t gx = (size_t)(rb*64 + i*8 + srow)*2048 + cb;
      size_t gw = (size_t)(i*8 + srow)*2048 + cb;
      GLDS16(xhg + gx, sm +         i*1024);
      GLDS16(xlg + gx, sm +  8192 + i*1024);
      GLDS16(w0h + gw, sm + 16384 + i*1024);
      GLDS16(w0l + gw, sm + 24576 + i*1024);
      GLDS16(w1h + gw, sm + 32768 + i*1024);
      GLDS16(w1l + gw, sm + 40960 + i*1024);
    }
    __syncthreads();
    #pragma unroll
    for (int ks = 0; ks < 2; ++ks){
      int ra = w*16 + lm;
      int offa = ra*128 + (((ks*4+quad) ^ (ra&7))*16);
      bf16x8 ah = *(const bf16x8*)(sm + offa);
      bf16x8 al = *(const bf16x8*)(sm + 8192 + offa);
      #pragma unroll
      for (int sub = 0; sub < 2; ++sub){
        #pragma unroll
        for (int n = 0; n < 4; ++n){
          int r = n*16 + lm;
          int off = r*128 + (((ks*4+quad) ^ (r&7))*16);
          bf16x8 bh = *(const bf16x8*)(sm + 16384 + sub*16384 + off);
          bf16x8 bl = *(const bf16x8*)(sm + 24576 + sub*16384 + off);
          acc[sub][n] = MFMA16(ah, bh, acc[sub][n]);
          acc[sub][n] = MFMA16(ah, bl, acc[sub][n]);
          acc[sub][n] = MFMA16(al, bh, acc[sub][n]);
        }
      }
    }
  }
  #pragma unroll
  for (int sub = 0; sub < 2; ++sub){
    int p = pg*2 + sub;
    if (p == 2 || p == 5){                   // raw f32 for Vu (slot 0) / Vc (slot 1)
      float* op = proj + (size_t)(p == 5 ? 1 : 0)*524288;
      #pragma unroll
      for (int n = 0; n < 4; ++n)
        #pragma unroll
        for (int e = 0; e < 4; ++e){
          int r = rb*64 + w*16 + quad*4 + e;
          op[(size_t)r*64 + n*16 + lm] = acc[sub][n][e];
        }
    }
    if (p != 5){
      unsigned short* oph = projh + (size_t)p*524288;
      unsigned short* opl = projl + (size_t)p*524288;
      #pragma unroll
      for (int n = 0; n < 4; ++n)
        #pragma unroll
        for (int e = 0; e < 4; ++e){
          int r = rb*64 + w*16 + quad*4 + e;
          float f = acc[sub][n][e];
          short hs = f2bf(f);
          oph[(size_t)r*64 + n*16 + lm] = (unsigned short)hs;
          opl[(size_t)r*64 + n*16 + lm] = (unsigned short)f2bf(f - bf2f(hs));
        }
    }
  }
}

// ---------------- P1b (fused): V_c -> vct fp16 ; V_u -> vuth/vutl fp16 h/l ----------------
__global__ void k_vt(const float* __restrict__ proj, _Float16* __restrict__ vct,
                     _Float16* __restrict__ vuth, _Float16* __restrict__ vutl){
  __shared__ float T[64][65];
  int b = blockIdx.y, stg = blockIdx.x;      // [0,64): 0-31 Vc, 32-63 Vu
  bool isVu = stg >= 32;
  int st = stg & 31;
  int tid = threadIdx.x;
  const float* src = proj + (isVu ? 0 : 524288) + (size_t)b*131072;
  int sloc = tid >> 2, cp = (tid & 3)*16;
  #pragma unroll
  for (int j = 0; j < 4; ++j){
    f32x4 v = *(const f32x4*)(src + (size_t)(st*64 + sloc)*64 + cp + j*4);
    #pragma unroll
    for (int e = 0; e < 4; ++e) T[sloc][cp + j*4 + e] = v[e];
  }
  __syncthreads();
  int d = tid >> 2, sp = (tid & 3)*16;
  size_t o = (size_t)b*131072 + (size_t)d*2048 + st*64 + sp;
  if (!isVu){
    f16x8 h0, h1;
    #pragma unroll
    for (int j = 0; j < 8; ++j) h0[j] = (_Float16)T[sp + j][d];
    #pragma unroll
    for (int j = 0; j < 8; ++j) h1[j] = (_Float16)T[sp + 8 + j][d];
    *(f16x8*)(vct + o) = h0; *(f16x8*)(vct + o + 8) = h1;
  } else {
    f16x8 h0, h1, l0, l1;
    #pragma unroll
    for (int j = 0; j < 8; ++j){
      float f = T[sp + j][d];
      _Float16 h = (_Float16)f;
      h0[j] = h; l0[j] = (_Float16)(f - (float)h);
    }
    #pragma unroll
    for (int j = 0; j < 8; ++j){
      float f = T[sp + 8 + j][d];
      _Float16 h = (_Float16)f;
      h1[j] = h; l1[j] = (_Float16)(f - (float)h);
    }
    *(f16x8*)(vuth + o) = h0; *(f16x8*)(vuth + o + 8) = h1;
    *(f16x8*)(vutl + o) = l0; *(f16x8*)(vutl + o + 8) = l1;
  }
}

// ---------------- P2: sig tiles (136, upper-tri) + raw diag t1 tiles (16) ----------------
__global__ __launch_bounds__(256,2) void k_p2(
    const unsigned short* __restrict__ ph, const unsigned short* __restrict__ pl,
    _Float16* __restrict__ sg, _Float16* __restrict__ t1d){
  __shared__ __align__(16) char sm[65536];
  int b = blockIdx.y;
  int t = blockIdx.x;                        // [0,152): 136 sig + 16 diag-t1
  bool isSig = t < 136;
  int a = 0, bb = 0;
  if (isSig){
    #pragma unroll 1
    for (int aa = 0; aa < 16; ++aa){
      int c = 16 - aa;
      if (t < c){ a = aa; bb = aa + t; break; }
      t -= c;
    }
  } else {
    a = bb = t - 136;
  }
  int pa = isSig ? 0 : 3;                    // A = Qu : Qc
  int pb = isSig ? 1 : 2;                    // B = Ku : Vu
  const char* Ahg = (const char*)ph + (size_t)pa*1048576;
  const char* Alg = (const char*)pl + (size_t)pa*1048576;
  const char* Bhg = (const char*)ph + (size_t)pb*1048576;
  const char* Blg = (const char*)pl + (size_t)pb*1048576;
  int tid = threadIdx.x, w = tid >> 6, lane = tid & 63;
  int lm = lane & 15, quad = lane >> 4;
  int srow = lane >> 3, scg = (lane & 7) ^ srow;
  int wm = (w & 1)*64, wn = (w >> 1)*64;
  #pragma unroll
  for (int i2 = 0; i2 < 4; ++i2){
    int i = w*4 + i2;
    int rl = i*8 + srow;
    size_t ga = (size_t)(b*2048 + a*128  + rl)*128 + scg*16;
    size_t gb = (size_t)(b*2048 + bb*128 + rl)*128 + scg*16;
    GLDS16(Ahg + ga, sm +         i*1024);
    GLDS16(Alg + ga, sm + 16384 + i*1024);
    GLDS16(Bhg + gb, sm + 32768 + i*1024);
    GLDS16(Blg + gb, sm + 49152 + i*1024);
  }
  __syncthreads();
  f32x4 acc[4][4] = {};
  #pragma unroll
  for (int ks = 0; ks < 2; ++ks){
    bf16x8 bh[4], bl[4];
    #pragma unroll
    for (int n = 0; n < 4; ++n){
      int r = wn + n*16 + lm;
      int off = r*128 + (((ks*4+quad) ^ (r&7))*16);
      bh[n] = *(const bf16x8*)(sm + 32768 + off);
      bl[n] = *(const bf16x8*)(sm + 49152 + off);
    }
    #pragma unroll
    for (int m = 0; m < 4; ++m){
      int r = wm + m*16 + lm;
      int off = r*128 + (((ks*4+quad) ^ (r&7))*16);
      bf16x8 ah = *(const bf16x8*)(sm + off);
      bf16x8 al = *(const bf16x8*)(sm + 16384 + off);
      #pragma unroll
      for (int n = 0; n < 4; ++n){
        acc[m][n] = MFMA16(ah, bh[n], acc[m][n]);
        acc[m][n] = MFMA16(ah, bl[n], acc[m][n]);
        acc[m][n] = MFMA16(al, bh[n], acc[m][n]);
      }
    }
  }
  __syncthreads();
  _Float16* Tt = (_Float16*)sm;              // 128x128 fp16 tile
  #pragma unroll
  for (int m = 0; m < 4; ++m){
    #pragma unroll
    for (int n = 0; n < 4; ++n){
      #pragma unroll
      for (int e = 0; e < 4; ++e){
        int il = wm + m*16 + quad*4 + e;
        int jl = wn + n*16 + lm;
        int gi = a*128 + il, gj = bb*128 + jl;
        float v = acc[m][n][e];
        float outv;
        if (isSig) outv = (gj >  gi) ? (1.0f/(1.0f + __expf(-v*0.125f))) : 0.0f;
        else       outv = (gj <= gi) ? v : 0.0f;   // raw (unscaled) diag t1
        Tt[il*128 + jl] = (_Float16)outv;
      }
    }
  }
  __syncthreads();
  char* outp = isSig
    ? (char*)(sg + (size_t)b*4194304 + (size_t)(a*128)*2048 + bb*128)
    : (char*)t1d + (size_t)(b*16 + a)*32768;
  size_t rstride = isSig ? 4096 : 256;       // bytes per row in dest
  #pragma unroll
  for (int r = 0; r < 8; ++r){
    int lrow = w*32 + r*4 + (lane >> 4);
    int c16 = lane & 15;
    f32x4 vv = *(const f32x4*)(sm + lrow*256 + c16*16);
    *(f32x4*)(outp + (size_t)lrow*rstride + c16*16) = vv;
  }
}

// ---------------- P2b-1: W[c][ck] = sig[k in ck, j in c] @ Vu[c]  (f32 out, all pairs parallel) ----------------
// pair p -> (c, ck) via tri decode; grid (136, B). 128k x 64d output, K=128.
__global__ __launch_bounds__(256) void k_w(
    const _Float16* __restrict__ sg,
    const _Float16* __restrict__ vuth, const _Float16* __restrict__ vutl,
    float* __restrict__ W){
  int p = blockIdx.x, b = blockIdx.y;
  int c = 0, ck = 0;
  #pragma unroll 1
  for (int aa = 0; aa < 16; ++aa){
    if (p < aa + 1){ c = aa; ck = p; break; }
    p -= aa + 1;
  }
  int pidx = blockIdx.x;
  int tid = threadIdx.x, w = tid >> 6, lane = tid & 63;
  int lm = lane & 15, quad = lane >> 4;
  int wm = (w & 1)*64, wn = (w >> 1)*32;     // 2k x 2d wave grid, 64x32 each
  const char* sgb = (const char*)sg + (size_t)b*8388608;
  f32x4 acc[4][2] = {};
  #pragma unroll
  for (int ks = 0; ks < 4; ++ks){
    f16x8 bh[2], bl[2];
    #pragma unroll
    for (int n = 0; n < 2; ++n){
      int d = wn + n*16 + lm;
      size_t jo = ((size_t)(b*64 + d)*2048 + c*128 + ks*32 + quad*8)*2;
      bh[n] = *(const f16x8*)((const char*)vuth + jo);
      bl[n] = *(const f16x8*)((const char*)vutl + jo);
    }
    #pragma unroll
    for (int m = 0; m < 4; ++m){
      int k = ck*128 + wm + m*16 + lm;
      f16x8 af = *(const f16x8*)(sgb + ((size_t)k*2048 + c*128 + ks*32 + quad*8)*2);
      #pragma unroll
      for (int n = 0; n < 2; ++n){
        acc[m][n] = MFMAF16(af, bh[n], acc[m][n]);
        acc[m][n] = MFMAF16(af, bl[n], acc[m][n]);
      }
    }
  }
  float* Wp = W + (size_t)(b*136 + pidx)*8192;
  #pragma unroll
  for (int m = 0; m < 4; ++m)
    #pragma unroll
    for (int n = 0; n < 2; ++n)
      #pragma unroll
      for (int e = 0; e < 4; ++e){
        int r = wm + m*16 + quad*4 + e;
        int col = wn + n*16 + lm;
        Wp[r*64 + col] = acc[m][n][e];
      }
}

// ---------------- P2b-2: parallel prefix P[ci][ck] = sum_{c in [ck,ci)} W[c][ck] -> bf16 h/l ----------------
// grid (64, B): x = ck*4 + ksub (32 k-rows each); pure streaming f32 adds, element-parallel.
__global__ __launch_bounds__(256) void k_scan(const float* __restrict__ W,
    unsigned short* __restrict__ Ph, unsigned short* __restrict__ Pl){
  int g = blockIdx.x, b = blockIdx.y;
  int ck = g >> 2, ksub = g & 3;
  if (ck >= 15) return;                      // ck=15 feeds nothing
  int tid = threadIdx.x;
  int rl = ksub*32 + (tid >> 3);             // row within 128-row chunk
  int col = (tid & 7)*8;
  float acc[8] = {};
  #pragma unroll 1
  for (int c = ck; c < 15; ++c){
    const float* wt = W + (size_t)(b*136 + c*(c+1)/2 + ck)*8192 + rl*64 + col;
    f32x4 v0 = *(const f32x4*)wt;
    f32x4 v1 = *(const f32x4*)(wt + 4);
    #pragma unroll
    for (int e = 0; e < 4; ++e){ acc[e] += v0[e]; acc[4+e] += v1[e]; }
    size_t o = ((size_t)(b*16 + c + 1)*2048 + ck*128 + rl)*64 + col;
    bf16x8 h, l;
    #pragma unroll
    for (int e = 0; e < 8; ++e){
      short hs = f2bf(acc[e]);
      h[e] = hs;
      l[e] = f2bf(acc[e] - bf2f(hs));
    }
    *(bf16x8*)(Ph + o) = h;
    *(bf16x8*)(Pl + o) = l;
  }
}

// ---------------- P3: logits tile (ci,ck) = s*Sc - silu(s*(Qc@P^T + t1d@sig^T)) ----------------
// Uniform work per tile: S_c (K=64) + rank-64 (skip if ci==ck) + diag correction (K=128 fp16).
// Also emits causal-masked row-max partials rmx[b][ck*2 + colhalf][row] (f32) so k_p4 can
// skip its max-sweep over the logits.
__global__ __launch_bounds__(256,2) void k_p3(
    const unsigned short* __restrict__ ph, const unsigned short* __restrict__ pl,
    const _Float16* __restrict__ t1d, const _Float16* __restrict__ sg,
    const unsigned short* __restrict__ Ph, const unsigned short* __restrict__ Pl,
    _Float16* __restrict__ lg, float* __restrict__ rmx){
  __shared__ __align__(16) char sm[32768];   // 128x128 fp16 logits tile
  int t = blockIdx.x, b = blockIdx.y;
  int ci = 0, ck = 0;
  #pragma unroll 1
  for (int aa = 0; aa < 16; ++aa){
    if (t < aa + 1){ ci = aa; ck = t; break; }
    t -= aa + 1;
  }
  int tid = threadIdx.x, w = tid >> 6, lane = tid & 63;
  int lm = lane & 15, quad = lane >> 4;
  int wm = (w & 1)*64, wn = (w >> 1)*64;
  f32x4 su[4][4] = {}, sc[4][4] = {};

  const char* Qh = (const char*)ph + (size_t)3*1048576;
  const char* Ql = (const char*)pl + (size_t)3*1048576;
  const char* Kh = (const char*)ph + (size_t)4*1048576;
  const char* Kl = (const char*)pl + (size_t)4*1048576;

  // ---- S_c = Qc @ Kc^T ----
  #pragma unroll
  for (int ks = 0; ks < 2; ++ks){
    bf16x8 kh[4], kl[4];
    #pragma unroll
    for (int n = 0; n < 4; ++n){
      size_t off = (size_t)(b*2048 + ck*128 + wn + n*16 + lm)*128 + (ks*32 + quad*8)*2;
      kh[n] = *(const bf16x8*)(Kh + off);
      kl[n] = *(const bf16x8*)(Kl + off);
    }
    #pragma unroll
    for (int m = 0; m < 4; ++m){
      size_t off = (size_t)(b*2048 + ci*128 + wm + m*16 + lm)*128 + (ks*32 + quad*8)*2;
      bf16x8 ah = *(const bf16x8*)(Qh + off);
      bf16x8 al = *(const bf16x8*)(Ql + off);
      #pragma unroll
      for (int n = 0; n < 4; ++n){
        sc[m][n] = MFMA16(ah, kh[n], sc[m][n]);
        sc[m][n] = MFMA16(ah, kl[n], sc[m][n]);
        sc[m][n] = MFMA16(al, kh[n], sc[m][n]);
      }
    }
  }
  // ---- rank-64 lower part: Qc @ P[ci]^T (zero on diagonal tiles; P unwritten there) ----
  if (ck < ci){
    #pragma unroll
    for (int ks = 0; ks < 2; ++ks){
      bf16x8 bh[4], bl[4];
      #pragma unroll
      for (int n = 0; n < 4; ++n){
        size_t off = (((size_t)(b*16 + ci)*2048 + ck*128 + wn + n*16 + lm)*64 + ks*32 + quad*8)*2;
        bh[n] = *(const bf16x8*)((const char*)Ph + off);
        bl[n] = *(const bf16x8*)((const char*)Pl + off);
      }
      #pragma unroll
      for (int m = 0; m < 4; ++m){
        size_t off = (size_t)(b*2048 + ci*128 + wm + m*16 + lm)*128 + (ks*32 + quad*8)*2;
        bf16x8 ah = *(const bf16x8*)(Qh + off);
        bf16x8 al = *(const bf16x8*)(Ql + off);
        #pragma unroll
        for (int n = 0; n < 4; ++n){
          su[m][n] = MFMA16(ah, bh[n], su[m][n]);
          su[m][n] = MFMA16(ah, bl[n], su[m][n]);
          su[m][n] = MFMA16(al, bh[n], su[m][n]);
        }
      }
    }
  }
  // ---- diag correction: t1d[ci] @ sig[ck-rows, ci-cols]^T (K=128 fp16) ----
  const char* t1b = (const char*)t1d + (size_t)(b*16 + ci)*32768;
  const char* sgb = (const char*)sg + (size_t)b*8388608;
  #pragma unroll
  for (int ks = 0; ks < 4; ++ks){
    f16x8 bs[4];
    #pragma unroll
    for (int n = 0; n < 4; ++n)
      bs[n] = *(const f16x8*)(sgb + ((size_t)(ck*128 + wn + n*16 + lm)*2048 + ci*128 + ks*32 + quad*8)*2);
    #pragma unroll
    for (int m = 0; m < 4; ++m){
      f16x8 at = *(const f16x8*)(t1b + ((wm + m*16 + lm)*128 + ks*32 + quad*8)*2);
      #pragma unroll
      for (int n = 0; n < 4; ++n)
        su[m][n] = MFMAF16(at, bs[n], su[m][n]);
    }
  }
  // ---- epilogue: logits to LDS + causal row-max partials (per wave: 64 rows x 64 cols) ----
  _Float16* Tt = (_Float16*)sm;
  bool diag = (ck == ci);
  #pragma unroll
  for (int m = 0; m < 4; ++m){
    #pragma unroll
    for (int e = 0; e < 4; ++e){
      int il = wm + m*16 + quad*4 + e;
      float vmax = -3.0e38f;
      #pragma unroll
      for (int n = 0; n < 4; ++n){
        int jl = wn + n*16 + lm;
        float xv = 0.125f*su[m][n][e];
        float sg1 = 1.0f/(1.0f + __expf(-xv));
        float val = sc[m][n][e]*0.125f - xv*sg1;
        Tt[il*128 + jl] = (_Float16)val;
        bool ok = !diag || (jl <= il);
        vmax = ok ? fmaxf(vmax, val) : vmax;
      }
      vmax = fmaxf(vmax, __shfl_xor(vmax, 1));
      vmax = fmaxf(vmax, __shfl_xor(vmax, 2));
      vmax = fmaxf(vmax, __shfl_xor(vmax, 4));
      vmax = fmaxf(vmax, __shfl_xor(vmax, 8));
      if (lm == m*4 + e)
        rmx[((size_t)b*32 + ck*2 + (w >> 1))*2048 + ci*128 + il] = vmax;
    }
  }
  __syncthreads();
  _Float16* lgb = lg + (size_t)b*4194304;
  #pragma unroll
  for (int r = 0; r < 8; ++r){
    int lrow = w*32 + r*4 + (lane >> 4);
    int c16 = lane & 15;
    f32x4 vv = *(const f32x4*)(sm + lrow*256 + c16*16);
    *(f32x4*)((char*)(lgb + (size_t)(ci*128 + lrow)*2048 + ck*128) + c16*16) = vv;
  }
}

// ---------------- P4 (fused): band softmax + P @ V_c, paired bands ----------------
// mfin gathered from rmx partials (no max-sweep); exp-sum folded into the PV pass
// (no sum-sweep): one LDS pass total instead of three.
__global__ __launch_bounds__(256,2) void k_p4(const _Float16* __restrict__ lg,
    const _Float16* __restrict__ vct, const float* __restrict__ rmx,
    float* __restrict__ out){
  __shared__ __align__(16) char sm[65792];   // Ls 64K | Sz 256B
  float* Sz = (float*)(sm + 65536);
  int b = blockIdx.y;
  int b1 = blockIdx.x;                       // 0..63; handles bands b1 and 127-b1
  int tid = threadIdx.x, w = tid >> 6, lane = tid & 63;
  int lm = lane & 15, quad = lane >> 4;
  const _Float16* vb = vct + (size_t)b*131072;
  for (int pass = 0; pass < 2; ++pass){
    int band = pass ? (127 - b1) : b1;
    int r0 = band*16;
    const char* lgb = (const char*)lg + ((size_t)b*4194304 + (size_t)r0*2048)*2;
    int nkt = ((r0 + 15) >> 6) + 1;
    int fc = (r0 + 1) >> 6;
    int srl = lane >> 3, ssl = lane & 7;
    __syncthreads();                          // LDS reuse vs previous pass
    for (int kt = w; kt < nkt; kt += 4){
      #pragma unroll
      for (int i2 = 0; i2 < 2; ++i2){
        int rl = i2*8 + srl;
        GLDS16(lgb + (size_t)rl*4096 + kt*128 + ((ssl ^ (rl & 7))*16),
               sm + kt*2048 + i2*1024);
      }
    }
    // row max for row r0+lm from rmx partials (overlaps the DMA)
    int ci2 = r0 >> 7;
    float mfin = -3.0e38f;
    {
      const float* rp = rmx + (size_t)b*32*2048 + r0 + lm;
      #pragma unroll 1
      for (int s = 0; s < 2*(ci2+1); ++s) mfin = fmaxf(mfin, rp[(size_t)s*2048]);
    }
    __syncthreads();
    // single pass: P = exp(L - mfin), sum folded in, PV MFMA
    float s_r = 0.0f;
    f32x4 acc[4] = {};
    for (int kt = w; kt < nkt; kt += 4){
      bool full = kt < fc;
      #pragma unroll
      for (int ks = 0; ks < 2; ++ks){
        f16x8 Lv = *(const f16x8*)(sm + kt*2048 + lm*128 + (((ks*4+quad) ^ (lm & 7))*16));
        int jbase = kt*64 + ks*32 + quad*8;
        f16x8 af;
        #pragma unroll
        for (int e = 0; e < 8; ++e){
          float p = __expf((float)Lv[e] - mfin);
          if (!full && (jbase + e > r0 + lm)) p = 0.0f;
          s_r += p;
          af[e] = (_Float16)p;
        }
        #pragma unroll
        for (int n = 0; n < 4; ++n){
          f16x8 bv = *(const f16x8*)(vb + (size_t)(n*16 + lm)*2048 + jbase);
          acc[n] = MFMAF16(af, bv, acc[n]);
        }
      }
    }
    s_r += __shfl_xor(s_r, 16);
    s_r += __shfl_xor(s_r, 32);
    Sz[w*16 + lm] = s_r;
    __syncthreads();
    float* Ot = (float*)sm;                  // [4][16][64], reuses dead Ls
    #pragma unroll
    for (int n = 0; n < 4; ++n)
      #pragma unroll
      for (int e = 0; e < 4; ++e)
        Ot[(w*16 + quad*4 + e)*64 + n*16 + lm] = acc[n][e];
    __syncthreads();
    int row = tid >> 4, c4 = (tid & 15)*4;
    f32x4 s = *(const f32x4*)&Ot[row*64 + c4];
    #pragma unroll
    for (int ww = 1; ww < 4; ++ww){
      f32x4 t2 = *(const f32x4*)&Ot[(ww*16 + row)*64 + c4];
      s[0]+=t2[0]; s[1]+=t2[1]; s[2]+=t2[2]; s[3]+=t2[3];
    }
    float z = Sz[row] + Sz[16 + row] + Sz[32 + row] + Sz[48 + row];
    f32x4 o = { s[0]/z, s[1]/z, s[2]/z, s[3]/z };
    *(f32x4*)(out + ((size_t)b*2048 + r0 + row)*64 + c4) = o;
  }
}

// ---------------- workspace layout (bytes) ----------------
static const size_t OFF_PROJ  = 0;           // 2 x 8192x64 f32 (Vu slot0, Vc slot1)
static const size_t OFF_WTH   = 4194304;     // 6 x 64x1024 bf16
static const size_t OFF_WTL   = 4980736;
static const size_t OFF_PROJH = 5767168;     // 6 x 8192x64 bf16
static const size_t OFF_PROJL = 12058624;
static const size_t OFF_VCT   = 18350080;    // 4 x 64x2048 f16
static const size_t OFF_SG    = 19398656;    // 4 x 2048^2 f16
static const size_t OFF_LG    = 52953088;    // 4 x 2048^2 f16
static const size_t OFF_T1D   = 86507520;    // 4 x 16 x 128x128 f16
static const size_t OFF_PH    = 88604672;    // 4 x 16 x 2048x64 bf16
static const size_t OFF_PL    = 105381888;
static const size_t OFF_VUTH  = 122159104;   // 4 x 64x2048 f16
static const size_t OFF_VUTL  = 123207680;
static const size_t OFF_XH    = 124256256;   // 8192x1024 bf16
static const size_t OFF_XL    = 141033472;
// W (4 x 136 x 128x64 f32 = 17,825,792 B) reuses the xh/xl region: k_proj is the
// last consumer of xh/xl, and k_w launches strictly after it in-stream.
static const size_t OFF_W     = OFF_XH;
static const size_t OFF_RMX   = 157810688;   // 4 x 32 x 2048 f32 row-max partials
// total = 158,859,264 bytes

extern "C" void kernel_launch(void* const* d_in, const int* in_sizes, int n_in,
                              void* d_out, int out_size, void* d_ws, size_t ws_size,
                              hipStream_t stream){
  (void)in_sizes; (void)n_in; (void)out_size; (void)ws_size;
  const float* x = (const float*)d_in[0];
  char* ws = (char*)d_ws;
  float*          proj  = (float*)(ws + OFF_PROJ);
  unsigned short* wth   = (unsigned short*)(ws + OFF_WTH);
  unsigned short* wtl   = (unsigned short*)(ws + OFF_WTL);
  unsigned short* projh = (unsigned short*)(ws + OFF_PROJH);
  unsigned short* projl = (unsigned short*)(ws + OFF_PROJL);
  _Float16*       vct   = (_Float16*)(ws + OFF_VCT);
  _Float16*       sg    = (_Float16*)(ws + OFF_SG);
  _Float16*       lg    = (_Float16*)(ws + OFF_LG);
  _Float16*       t1d   = (_Float16*)(ws + OFF_T1D);
  unsigned short* Phb   = (unsigned short*)(ws + OFF_PH);
  unsigned short* Plb   = (unsigned short*)(ws + OFF_PL);
  _Float16*       vuth  = (_Float16*)(ws + OFF_VUTH);
  _Float16*       vutl  = (_Float16*)(ws + OFF_VUTL);
  unsigned short* xh    = (unsigned short*)(ws + OFF_XH);
  unsigned short* xl    = (unsigned short*)(ws + OFF_XL);
  float*          Wb    = (float*)(ws + OFF_W);
  float*          rmx   = (float*)(ws + OFF_RMX);

  k_wt    <<<dim3(256,6),  256, 0, stream>>>((const float*)d_in[1], (const float*)d_in[2],
                                             (const float*)d_in[3], (const float*)d_in[4],
                                             (const float*)d_in[5], (const float*)d_in[6], wth, wtl);
  k_xsplit<<<dim3(4096),   256, 0, stream>>>(x, xh, xl);
  k_proj  <<<dim3(384),    256, 0, stream>>>(xh, xl, wth, wtl, proj, projh, projl);
  k_vt    <<<dim3(64,4),   256, 0, stream>>>(proj, vct, vuth, vutl);
  k_p2    <<<dim3(152,4),  256, 0, stream>>>(projh, projl, sg, t1d);
  k_w     <<<dim3(136,4),  256, 0, stream>>>(sg, vuth, vutl, Wb);
  k_scan  <<<dim3(64,4),   256, 0, stream>>>(Wb, Phb, Plb);
  k_p3    <<<dim3(136,4),  256, 0, stream>>>(projh, projl, t1d, sg, Phb, Plb, lg, rmx);
  k_p4    <<<dim3(64,4),   256, 0, stream>>>(lg, vct, rmx, (float*)d_out);
}

// Round 7
// 205.794 us; speedup vs baseline: 1.1021x; 1.1021x over previous
//
#include <hip/hip_runtime.h>
#include <hip/hip_bf16.h>

// B=4, S=2048, D=1024, DH=64. Inputs/outputs are FLOAT32 (per reference).
typedef short bf16x8 __attribute__((ext_vector_type(8)));
typedef float f32x4  __attribute__((ext_vector_type(4)));
typedef _Float16 f16x8 __attribute__((ext_vector_type(8)));

#define MFMA16(a,b,c)  __builtin_amdgcn_mfma_f32_16x16x32_bf16((a),(b),(c),0,0,0)
#define MFMAF16(a,b,c) __builtin_amdgcn_mfma_f32_16x16x32_f16((a),(b),(c),0,0,0)

// async global->LDS: 16B per lane, lane i lands at lds_base + i*16
#define GLDS16(g,l) __builtin_amdgcn_global_load_lds( \
    (const __attribute__((address_space(1))) void*)(g), \
    (__attribute__((address_space(3))) void*)(l), 16, 0, 0)

__device__ __forceinline__ short f2bf(float f){
  union { float f; unsigned u; } v; v.f = f;
  unsigned r = v.u + 0x7fffu + ((v.u >> 16) & 1u);
  return (short)(r >> 16);
}
__device__ __forceinline__ float bf2f(short h){
  union { unsigned u; float f; } v; v.u = ((unsigned)(unsigned short)h) << 16;
  return v.f;
}
__device__ __forceinline__ void split8v(f32x4 a, f32x4 b, bf16x8& h, bf16x8& l){
  float t[8] = {a[0],a[1],a[2],a[3],b[0],b[1],b[2],b[3]};
  #pragma unroll
  for (int e = 0; e < 8; ++e){
    short hs = f2bf(t[e]);
    h[e] = hs;
    l[e] = f2bf(t[e] - bf2f(hs));
  }
}

// ---------------- P0 (fused): weight transpose+split (blocks 0..1535) + x split (1536..5631) ----------------
__global__ void k_prep(const float* w0, const float* w1, const float* w2,
                       const float* w3, const float* w4, const float* w5,
                       const float* __restrict__ x,
                       unsigned short* __restrict__ wth, unsigned short* __restrict__ wtl,
                       unsigned short* __restrict__ xh, unsigned short* __restrict__ xl){
  int gb = blockIdx.x;
  if (gb < 1536){
    int p = gb >> 8;
    const float* wp = p==0?w0:p==1?w1:p==2?w2:p==3?w3:p==4?w4:w5;
    int idx = (gb & 255)*256 + threadIdx.x;   // [0,65536)
    int n = idx >> 10, k = idx & 1023;
    float v = wp[k*64 + n];
    short hs = f2bf(v);
    wth[(size_t)p*65536 + n*1024 + k] = (unsigned short)hs;
    wtl[(size_t)p*65536 + n*1024 + k] = (unsigned short)f2bf(v - bf2f(hs));
  } else {
    size_t i = ((size_t)(gb - 1536)*256 + threadIdx.x)*8;
    f32x4 a = *(const f32x4*)(x + i);
    f32x4 b = *(const f32x4*)(x + i + 4);
    bf16x8 h, l;
    split8v(a, b, h, l);
    *(bf16x8*)(xh + i) = h;
    *(bf16x8*)(xl + i) = l;
  }
}

// ---------------- P1: projections + fused V-transpose epilogue ----------------
// bf16 h/l out for p 0..4; pg==1 blocks also emit Vu^T fp16 h/l; pg==2 blocks emit Vc^T fp16.
__global__ __launch_bounds__(256) void k_proj(
    const unsigned short* __restrict__ xh, const unsigned short* __restrict__ xl,
    const unsigned short* __restrict__ wth, const unsigned short* __restrict__ wtl,
    unsigned short* __restrict__ projh, unsigned short* __restrict__ projl,
    _Float16* __restrict__ vct, _Float16* __restrict__ vuth, _Float16* __restrict__ vutl){
  __shared__ __align__(16) char sm[49152];  // xh 8K | xl 8K | w0h 8K | w0l 8K | w1h 8K | w1l 8K
  int blk = blockIdx.x;
  int rb = blk/3, pg = blk - rb*3;
  int tid = threadIdx.x, w = tid >> 6, lane = tid & 63;
  int lm = lane & 15, quad = lane >> 4;
  int srow = lane >> 3, scg = (lane & 7) ^ srow;
  const char* xhg = (const char*)xh;
  const char* xlg = (const char*)xl;
  const char* w0h = (const char*)wth + (size_t)(pg*2  )*131072;
  const char* w0l = (const char*)wtl + (size_t)(pg*2  )*131072;
  const char* w1h = (const char*)wth + (size_t)(pg*2+1)*131072;
  const char* w1l = (const char*)wtl + (size_t)(pg*2+1)*131072;
  f32x4 acc[2][4] = {};
  for (int k0 = 0; k0 < 1024; k0 += 64){
    __syncthreads();
    size_t cb = (size_t)k0*2 + scg*16;
    #pragma unroll
    for (int i2 = 0; i2 < 2; ++i2){
      int i = w*2 + i2;
      size_t gx = (size_t)(rb*64 + i*8 + srow)*2048 + cb;
      size_t gw = (size_t)(i*8 + srow)*2048 + cb;
      GLDS16(xhg + gx, sm +         i*1024);
      GLDS16(xlg + gx, sm +  8192 + i*1024);
      GLDS16(w0h + gw, sm + 16384 + i*1024);
      GLDS16(w0l + gw, sm + 24576 + i*1024);
      GLDS16(w1h + gw, sm + 32768 + i*1024);
      GLDS16(w1l + gw, sm + 40960 + i*1024);
    }
    __syncthreads();
    #pragma unroll
    for (int ks = 0; ks < 2; ++ks){
      int ra = w*16 + lm;
      int offa = ra*128 + (((ks*4+quad) ^ (ra&7))*16);
      bf16x8 ah = *(const bf16x8*)(sm + offa);
      bf16x8 al = *(const bf16x8*)(sm + 8192 + offa);
      #pragma unroll
      for (int sub = 0; sub < 2; ++sub){
        #pragma unroll
        for (int n = 0; n < 4; ++n){
          int r = n*16 + lm;
          int off = r*128 + (((ks*4+quad) ^ (r&7))*16);
          bf16x8 bh = *(const bf16x8*)(sm + 16384 + sub*16384 + off);
          bf16x8 bl = *(const bf16x8*)(sm + 24576 + sub*16384 + off);
          acc[sub][n] = MFMA16(ah, bh, acc[sub][n]);
          acc[sub][n] = MFMA16(ah, bl, acc[sub][n]);
          acc[sub][n] = MFMA16(al, bh, acc[sub][n]);
        }
      }
    }
  }
  #pragma unroll
  for (int sub = 0; sub < 2; ++sub){
    int p = pg*2 + sub;
    if (p != 5){
      unsigned short* oph = projh + (size_t)p*524288;
      unsigned short* opl = projl + (size_t)p*524288;
      #pragma unroll
      for (int n = 0; n < 4; ++n)
        #pragma unroll
        for (int e = 0; e < 4; ++e){
          int r = rb*64 + w*16 + quad*4 + e;
          float f = acc[sub][n][e];
          short hs = f2bf(f);
          oph[(size_t)r*64 + n*16 + lm] = (unsigned short)hs;
          opl[(size_t)r*64 + n*16 + lm] = (unsigned short)f2bf(f - bf2f(hs));
        }
    }
  }
  // fused transpose: pg==1 -> Vu (sub 0) to vuth/vutl; pg==2 -> Vc (sub 1) to vct
  if (pg == 1 || pg == 2){
    int sub = (pg == 1) ? 0 : 1;
    float (*T)[65] = (float (*)[65])sm;
    __syncthreads();                          // main-loop LDS reads done
    #pragma unroll
    for (int n = 0; n < 4; ++n)
      #pragma unroll
      for (int e = 0; e < 4; ++e)
        T[w*16 + quad*4 + e][n*16 + lm] = acc[sub][n][e];
    __syncthreads();
    int b2 = rb >> 5, sl = (rb & 31)*64;
    int d = tid >> 2, sp = (tid & 3)*16;
    size_t o = (size_t)b2*131072 + (size_t)d*2048 + sl + sp;
    if (sub == 1){
      f16x8 h0, h1;
      #pragma unroll
      for (int j = 0; j < 8; ++j) h0[j] = (_Float16)T[sp + j][d];
      #pragma unroll
      for (int j = 0; j < 8; ++j) h1[j] = (_Float16)T[sp + 8 + j][d];
      *(f16x8*)(vct + o) = h0; *(f16x8*)(vct + o + 8) = h1;
    } else {
      f16x8 h0, h1, l0, l1;
      #pragma unroll
      for (int j = 0; j < 8; ++j){
        float f = T[sp + j][d];
        _Float16 h = (_Float16)f;
        h0[j] = h; l0[j] = (_Float16)(f - (float)h);
      }
      #pragma unroll
      for (int j = 0; j < 8; ++j){
        float f = T[sp + 8 + j][d];
        _Float16 h = (_Float16)f;
        h1[j] = h; l1[j] = (_Float16)(f - (float)h);
      }
      *(f16x8*)(vuth + o) = h0; *(f16x8*)(vuth + o + 8) = h1;
      *(f16x8*)(vutl + o) = l0; *(f16x8*)(vutl + o + 8) = l1;
    }
  }
}

// ---------------- P2: sig tiles (136) + diag t1 tiles (16), with FUSED W-GEMM ----------------
// Sig tile (a,bb) is exactly the A-operand of W[(c=bb,ck=a)] = sig @ Vu^T[bb]; compute it
// from the LDS tile (XOR-swizzled so K-dim f16x8 reads are ~conflict-free) and store W f32.
__global__ __launch_bounds__(256,2) void k_p2(
    const unsigned short* __restrict__ ph, const unsigned short* __restrict__ pl,
    const _Float16* __restrict__ vuth, const _Float16* __restrict__ vutl,
    _Float16* __restrict__ sg, _Float16* __restrict__ t1d, float* __restrict__ W){
  __shared__ __align__(16) char sm[65536];
  int b = blockIdx.y;
  int t = blockIdx.x;                        // [0,152): 136 sig + 16 diag-t1
  bool isSig = t < 136;
  int a = 0, bb = 0;
  if (isSig){
    #pragma unroll 1
    for (int aa = 0; aa < 16; ++aa){
      int c = 16 - aa;
      if (t < c){ a = aa; bb = aa + t; break; }
      t -= c;
    }
  } else {
    a = bb = t - 136;
  }
  int pa = isSig ? 0 : 3;                    // A = Qu : Qc
  int pb = isSig ? 1 : 2;                    // B = Ku : Vu
  const char* Ahg = (const char*)ph + (size_t)pa*1048576;
  const char* Alg = (const char*)pl + (size_t)pa*1048576;
  const char* Bhg = (const char*)ph + (size_t)pb*1048576;
  const char* Blg = (const char*)pl + (size_t)pb*1048576;
  int tid = threadIdx.x, w = tid >> 6, lane = tid & 63;
  int lm = lane & 15, quad = lane >> 4;
  int srow = lane >> 3, scg = (lane & 7) ^ srow;
  int wm = (w & 1)*64, wn = (w >> 1)*64;
  #pragma unroll
  for (int i2 = 0; i2 < 4; ++i2){
    int i = w*4 + i2;
    int rl = i*8 + srow;
    size_t ga = (size_t)(b*2048 + a*128  + rl)*128 + scg*16;
    size_t gb = (size_t)(b*2048 + bb*128 + rl)*128 + scg*16;
    GLDS16(Ahg + ga, sm +         i*1024);
    GLDS16(Alg + ga, sm + 16384 + i*1024);
    GLDS16(Bhg + gb, sm + 32768 + i*1024);
    GLDS16(Blg + gb, sm + 49152 + i*1024);
  }
  __syncthreads();
  f32x4 acc[4][4] = {};
  #pragma unroll
  for (int ks = 0; ks < 2; ++ks){
    bf16x8 bh[4], bl[4];
    #pragma unroll
    for (int n = 0; n < 4; ++n){
      int r = wn + n*16 + lm;
      int off = r*128 + (((ks*4+quad) ^ (r&7))*16);
      bh[n] = *(const bf16x8*)(sm + 32768 + off);
      bl[n] = *(const bf16x8*)(sm + 49152 + off);
    }
    #pragma unroll
    for (int m = 0; m < 4; ++m){
      int r = wm + m*16 + lm;
      int off = r*128 + (((ks*4+quad) ^ (r&7))*16);
      bf16x8 ah = *(const bf16x8*)(sm + off);
      bf16x8 al = *(const bf16x8*)(sm + 16384 + off);
      #pragma unroll
      for (int n = 0; n < 4; ++n){
        acc[m][n] = MFMA16(ah, bh[n], acc[m][n]);
        acc[m][n] = MFMA16(ah, bl[n], acc[m][n]);
        acc[m][n] = MFMA16(al, bh[n], acc[m][n]);
      }
    }
  }
  __syncthreads();
  // swizzled 128x128 f16 tile: byte ^= (row&7)<<4
  #pragma unroll
  for (int m = 0; m < 4; ++m){
    #pragma unroll
    for (int n = 0; n < 4; ++n){
      #pragma unroll
      for (int e = 0; e < 4; ++e){
        int il = wm + m*16 + quad*4 + e;
        int jl = wn + n*16 + lm;
        int gi = a*128 + il, gj = bb*128 + jl;
        float v = acc[m][n][e];
        float outv;
        if (isSig) outv = (gj >  gi) ? (1.0f/(1.0f + __expf(-v*0.125f))) : 0.0f;
        else       outv = (gj <= gi) ? v : 0.0f;   // raw (unscaled) diag t1
        *(_Float16*)(sm + ((il*256 + jl*2) ^ ((il & 7) << 4))) = (_Float16)outv;
      }
    }
  }
  __syncthreads();
  char* outp = isSig
    ? (char*)(sg + (size_t)b*4194304 + (size_t)(a*128)*2048 + bb*128)
    : (char*)t1d + (size_t)(b*16 + a)*32768;
  size_t rstride = isSig ? 4096 : 256;       // bytes per row in dest
  #pragma unroll
  for (int r = 0; r < 8; ++r){
    int lrow = w*32 + r*4 + (lane >> 4);
    int c16 = lane & 15;
    f32x4 vv = *(const f32x4*)(sm + ((lrow*256 + c16*16) ^ ((lrow & 7) << 4)));
    *(f32x4*)(outp + (size_t)lrow*rstride + c16*16) = vv;
  }
  // fused W-GEMM: W[(c=bb,ck=a)] = sig_tile (LDS) @ Vu^T[bb], 128k x 64d, K=128 fp16 h/l
  if (isSig){
    int wm2 = (w & 1)*64, wn2 = (w >> 1)*32;
    f32x4 acc2[4][2] = {};
    #pragma unroll
    for (int ks = 0; ks < 4; ++ks){
      f16x8 bh2[2], bl2[2];
      #pragma unroll
      for (int n = 0; n < 2; ++n){
        int d = wn2 + n*16 + lm;
        size_t jo = ((size_t)(b*64 + d)*2048 + bb*128 + ks*32 + quad*8)*2;
        bh2[n] = *(const f16x8*)((const char*)vuth + jo);
        bl2[n] = *(const f16x8*)((const char*)vutl + jo);
      }
      #pragma unroll
      for (int m = 0; m < 4; ++m){
        int k = wm2 + m*16 + lm;
        f16x8 af = *(const f16x8*)(sm + ((k*256 + ks*64 + quad*16) ^ ((k & 7) << 4)));
        #pragma unroll
        for (int n = 0; n < 2; ++n){
          acc2[m][n] = MFMAF16(af, bh2[n], acc2[m][n]);
          acc2[m][n] = MFMAF16(af, bl2[n], acc2[m][n]);
        }
      }
    }
    float* Wp = W + (size_t)(b*136 + bb*(bb+1)/2 + a)*8192;
    #pragma unroll
    for (int m = 0; m < 4; ++m)
      #pragma unroll
      for (int n = 0; n < 2; ++n)
        #pragma unroll
        for (int e = 0; e < 4; ++e){
          int r = wm2 + m*16 + quad*4 + e;
          int col = wn2 + n*16 + lm;
          Wp[r*64 + col] = acc2[m][n][e];
        }
  }
}

// ---------------- P2b: parallel prefix P[ci][ck] = sum_{c in [ck,ci)} W[c][ck] -> bf16 h/l ----------------
__global__ __launch_bounds__(256) void k_scan(const float* __restrict__ W,
    unsigned short* __restrict__ Ph, unsigned short* __restrict__ Pl){
  int g = blockIdx.x, b = blockIdx.y;
  int ck = g >> 2, ksub = g & 3;
  if (ck >= 15) return;                      // ck=15 feeds nothing
  int tid = threadIdx.x;
  int rl = ksub*32 + (tid >> 3);             // row within 128-row chunk
  int col = (tid & 7)*8;
  float acc[8] = {};
  #pragma unroll 1
  for (int c = ck; c < 15; ++c){
    const float* wt = W + (size_t)(b*136 + c*(c+1)/2 + ck)*8192 + rl*64 + col;
    f32x4 v0 = *(const f32x4*)wt;
    f32x4 v1 = *(const f32x4*)(wt + 4);
    #pragma unroll
    for (int e = 0; e < 4; ++e){ acc[e] += v0[e]; acc[4+e] += v1[e]; }
    size_t o = ((size_t)(b*16 + c + 1)*2048 + ck*128 + rl)*64 + col;
    bf16x8 h, l;
    #pragma unroll
    for (int e = 0; e < 8; ++e){
      short hs = f2bf(acc[e]);
      h[e] = hs;
      l[e] = f2bf(acc[e] - bf2f(hs));
    }
    *(bf16x8*)(Ph + o) = h;
    *(bf16x8*)(Pl + o) = l;
  }
}

// ---------------- P3: logits tile (ci,ck) = s*Sc - silu(s*(Qc@P^T + t1d@sig^T)) ----------------
__global__ __launch_bounds__(256,2) void k_p3(
    const unsigned short* __restrict__ ph, const unsigned short* __restrict__ pl,
    const _Float16* __restrict__ t1d, const _Float16* __restrict__ sg,
    const unsigned short* __restrict__ Ph, const unsigned short* __restrict__ Pl,
    _Float16* __restrict__ lg){
  __shared__ __align__(16) char sm[32768];   // 128x128 fp16 logits tile
  int t = blockIdx.x, b = blockIdx.y;
  int ci = 0, ck = 0;
  #pragma unroll 1
  for (int aa = 0; aa < 16; ++aa){
    if (t < aa + 1){ ci = aa; ck = t; break; }
    t -= aa + 1;
  }
  int tid = threadIdx.x, w = tid >> 6, lane = tid & 63;
  int lm = lane & 15, quad = lane >> 4;
  int wm = (w & 1)*64, wn = (w >> 1)*64;
  f32x4 su[4][4] = {}, sc[4][4] = {};

  const char* Qh = (const char*)ph + (size_t)3*1048576;
  const char* Ql = (const char*)pl + (size_t)3*1048576;
  const char* Kh = (const char*)ph + (size_t)4*1048576;
  const char* Kl = (const char*)pl + (size_t)4*1048576;

  // ---- S_c = Qc @ Kc^T ----
  #pragma unroll
  for (int ks = 0; ks < 2; ++ks){
    bf16x8 kh[4], kl[4];
    #pragma unroll
    for (int n = 0; n < 4; ++n){
      size_t off = (size_t)(b*2048 + ck*128 + wn + n*16 + lm)*128 + (ks*32 + quad*8)*2;
      kh[n] = *(const bf16x8*)(Kh + off);
      kl[n] = *(const bf16x8*)(Kl + off);
    }
    #pragma unroll
    for (int m = 0; m < 4; ++m){
      size_t off = (size_t)(b*2048 + ci*128 + wm + m*16 + lm)*128 + (ks*32 + quad*8)*2;
      bf16x8 ah = *(const bf16x8*)(Qh + off);
      bf16x8 al = *(const bf16x8*)(Ql + off);
      #pragma unroll
      for (int n = 0; n < 4; ++n){
        sc[m][n] = MFMA16(ah, kh[n], sc[m][n]);
        sc[m][n] = MFMA16(ah, kl[n], sc[m][n]);
        sc[m][n] = MFMA16(al, kh[n], sc[m][n]);
      }
    }
  }
  // ---- rank-64 lower part: Qc @ P[ci]^T (zero on diagonal tiles; P unwritten there) ----
  if (ck < ci){
    #pragma unroll
    for (int ks = 0; ks < 2; ++ks){
      bf16x8 bh[4], bl[4];
      #pragma unroll
      for (int n = 0; n < 4; ++n){
        size_t off = (((size_t)(b*16 + ci)*2048 + ck*128 + wn + n*16 + lm)*64 + ks*32 + quad*8)*2;
        bh[n] = *(const bf16x8*)((const char*)Ph + off);
        bl[n] = *(const bf16x8*)((const char*)Pl + off);
      }
      #pragma unroll
      for (int m = 0; m < 4; ++m){
        size_t off = (size_t)(b*2048 + ci*128 + wm + m*16 + lm)*128 + (ks*32 + quad*8)*2;
        bf16x8 ah = *(const bf16x8*)(Qh + off);
        bf16x8 al = *(const bf16x8*)(Ql + off);
        #pragma unroll
        for (int n = 0; n < 4; ++n){
          su[m][n] = MFMA16(ah, bh[n], su[m][n]);
          su[m][n] = MFMA16(ah, bl[n], su[m][n]);
          su[m][n] = MFMA16(al, bh[n], su[m][n]);
        }
      }
    }
  }
  // ---- diag correction: t1d[ci] @ sig[ck-rows, ci-cols]^T (K=128 fp16) ----
  const char* t1b = (const char*)t1d + (size_t)(b*16 + ci)*32768;
  const char* sgb = (const char*)sg + (size_t)b*8388608;
  #pragma unroll
  for (int ks = 0; ks < 4; ++ks){
    f16x8 bs[4];
    #pragma unroll
    for (int n = 0; n < 4; ++n)
      bs[n] = *(const f16x8*)(sgb + ((size_t)(ck*128 + wn + n*16 + lm)*2048 + ci*128 + ks*32 + quad*8)*2);
    #pragma unroll
    for (int m = 0; m < 4; ++m){
      f16x8 at = *(const f16x8*)(t1b + ((wm + m*16 + lm)*128 + ks*32 + quad*8)*2);
      #pragma unroll
      for (int n = 0; n < 4; ++n)
        su[m][n] = MFMAF16(at, bs[n], su[m][n]);
    }
  }
  // ---- epilogue ----
  _Float16* Tt = (_Float16*)sm;
  #pragma unroll
  for (int m = 0; m < 4; ++m)
    #pragma unroll
    for (int n = 0; n < 4; ++n)
      #pragma unroll
      for (int e = 0; e < 4; ++e){
        int il = wm + m*16 + quad*4 + e;
        int jl = wn + n*16 + lm;
        float xv = 0.125f*su[m][n][e];
        float sg1 = 1.0f/(1.0f + __expf(-xv));
        Tt[il*128 + jl] = (_Float16)(sc[m][n][e]*0.125f - xv*sg1);
      }
  __syncthreads();
  _Float16* lgb = lg + (size_t)b*4194304;
  #pragma unroll
  for (int r = 0; r < 8; ++r){
    int lrow = w*32 + r*4 + (lane >> 4);
    int c16 = lane & 15;
    f32x4 vv = *(const f32x4*)(sm + lrow*256 + c16*16);
    *(f32x4*)((char*)(lgb + (size_t)(ci*128 + lrow)*2048 + ck*128) + c16*16) = vv;
  }
}

// ---------------- P4 (fused): band softmax + P @ V_c, paired bands for balance ----------------
__global__ __launch_bounds__(256,2) void k_p4(const _Float16* __restrict__ lg,
    const _Float16* __restrict__ vct, float* __restrict__ out){
  __shared__ __align__(16) char sm[66048];   // Ls 64K | Mz 256B | Sz 256B
  float* Mz = (float*)(sm + 65536);
  float* Sz = (float*)(sm + 65792);
  int b = blockIdx.y;
  int b1 = blockIdx.x;                       // 0..63; handles bands b1 and 127-b1
  int tid = threadIdx.x, w = tid >> 6, lane = tid & 63;
  int lm = lane & 15, quad = lane >> 4;
  const _Float16* vb = vct + (size_t)b*131072;
  for (int pass = 0; pass < 2; ++pass){
    int band = pass ? (127 - b1) : b1;
    int r0 = band*16;
    const char* lgb = (const char*)lg + ((size_t)b*4194304 + (size_t)r0*2048)*2;
    int nkt = ((r0 + 15) >> 6) + 1;
    int fc = (r0 + 1) >> 6;
    int srl = lane >> 3, ssl = lane & 7;
    __syncthreads();                          // LDS reuse vs previous pass
    for (int kt = w; kt < nkt; kt += 4){
      #pragma unroll
      for (int i2 = 0; i2 < 2; ++i2){
        int rl = i2*8 + srl;
        GLDS16(lgb + (size_t)rl*4096 + kt*128 + ((ssl ^ (rl & 7))*16),
               sm + kt*2048 + i2*1024);
      }
    }
    __syncthreads();
    // sweep 1: causal row max
    float m_r = -3.0e38f;
    for (int kt = w; kt < nkt; kt += 4){
      #pragma unroll
      for (int half = 0; half < 2; ++half){
        int sl = quad*2 + half;
        f16x8 v = *(const f16x8*)(sm + kt*2048 + lm*128 + ((sl ^ (lm & 7))*16));
        int cb = kt*64 + sl*8;
        #pragma unroll
        for (int e = 0; e < 8; ++e)
          m_r = (cb + e <= r0 + lm) ? fmaxf(m_r, (float)v[e]) : m_r;
      }
    }
    m_r = fmaxf(m_r, __shfl_xor(m_r, 16));
    m_r = fmaxf(m_r, __shfl_xor(m_r, 32));
    Mz[w*16 + lm] = m_r;
    __syncthreads();
    float mfin = fmaxf(fmaxf(Mz[lm], Mz[16 + lm]), fmaxf(Mz[32 + lm], Mz[48 + lm]));
    // sweep 2: sum of exp(x - mfin)
    float s_r = 0.0f;
    for (int kt = w; kt < nkt; kt += 4){
      #pragma unroll
      for (int half = 0; half < 2; ++half){
        int sl = quad*2 + half;
        f16x8 v = *(const f16x8*)(sm + kt*2048 + lm*128 + ((sl ^ (lm & 7))*16));
        int cb = kt*64 + sl*8;
        #pragma unroll
        for (int e = 0; e < 8; ++e)
          if (cb + e <= r0 + lm) s_r += __expf((float)v[e] - mfin);
      }
    }
    s_r += __shfl_xor(s_r, 16);
    s_r += __shfl_xor(s_r, 32);
    Sz[w*16 + lm] = s_r;
    // MFMA P @ V^T, chunks striped across waves
    f32x4 acc[4] = {};
    for (int kt = w; kt < nkt; kt += 4){
      bool full = kt < fc;
      #pragma unroll
      for (int ks = 0; ks < 2; ++ks){
        f16x8 Lv = *(const f16x8*)(sm + kt*2048 + lm*128 + (((ks*4+quad) ^ (lm & 7))*16));
        int jbase = kt*64 + ks*32 + quad*8;
        f16x8 af;
        #pragma unroll
        for (int e = 0; e < 8; ++e){
          float p = __expf((float)Lv[e] - mfin);
          if (!full && (jbase + e > r0 + lm)) p = 0.0f;
          af[e] = (_Float16)p;
        }
        #pragma unroll
        for (int n = 0; n < 4; ++n){
          f16x8 bv = *(const f16x8*)(vb + (size_t)(n*16 + lm)*2048 + jbase);
          acc[n] = MFMAF16(af, bv, acc[n]);
        }
      }
    }
    __syncthreads();
    float* Ot = (float*)sm;                  // [4][16][64], reuses dead Ls
    #pragma unroll
    for (int n = 0; n < 4; ++n)
      #pragma unroll
      for (int e = 0; e < 4; ++e)
        Ot[(w*16 + quad*4 + e)*64 + n*16 + lm] = acc[n][e];
    __syncthreads();
    int row = tid >> 4, c4 = (tid & 15)*4;
    f32x4 s = *(const f32x4*)&Ot[row*64 + c4];
    #pragma unroll
    for (int ww = 1; ww < 4; ++ww){
      f32x4 t2 = *(const f32x4*)&Ot[(ww*16 + row)*64 + c4];
      s[0]+=t2[0]; s[1]+=t2[1]; s[2]+=t2[2]; s[3]+=t2[3];
    }
    float z = Sz[row] + Sz[16 + row] + Sz[32 + row] + Sz[48 + row];
    f32x4 o = { s[0]/z, s[1]/z, s[2]/z, s[3]/z };
    *(f32x4*)(out + ((size_t)b*2048 + r0 + row)*64 + c4) = o;
  }
}

// ---------------- workspace layout (bytes) ----------------
static const size_t OFF_WTH   = 4194304;     // 6 x 64x1024 bf16
static const size_t OFF_WTL   = 4980736;
static const size_t OFF_PROJH = 5767168;     // 6 x 8192x64 bf16
static const size_t OFF_PROJL = 12058624;
static const size_t OFF_VCT   = 18350080;    // 4 x 64x2048 f16
static const size_t OFF_SG    = 19398656;    // 4 x 2048^2 f16
static const size_t OFF_LG    = 52953088;    // 4 x 2048^2 f16
static const size_t OFF_T1D   = 86507520;    // 4 x 16 x 128x128 f16
static const size_t OFF_PH    = 88604672;    // 4 x 16 x 2048x64 bf16
static const size_t OFF_PL    = 105381888;
static const size_t OFF_VUTH  = 122159104;   // 4 x 64x2048 f16
static const size_t OFF_VUTL  = 123207680;
static const size_t OFF_XH    = 124256256;   // 8192x1024 bf16
static const size_t OFF_XL    = 141033472;
// W (4 x 136 x 128x64 f32 = 17,825,792 B) reuses the xh/xl region: k_proj is the
// last consumer of xh/xl; k_p2 (the W producer) launches strictly after it in-stream.
static const size_t OFF_W     = OFF_XH;
// total = 157,810,688 bytes

extern "C" void kernel_launch(void* const* d_in, const int* in_sizes, int n_in,
                              void* d_out, int out_size, void* d_ws, size_t ws_size,
                              hipStream_t stream){
  (void)in_sizes; (void)n_in; (void)out_size; (void)ws_size;
  const float* x = (const float*)d_in[0];
  char* ws = (char*)d_ws;
  unsigned short* wth   = (unsigned short*)(ws + OFF_WTH);
  unsigned short* wtl   = (unsigned short*)(ws + OFF_WTL);
  unsigned short* projh = (unsigned short*)(ws + OFF_PROJH);
  unsigned short* projl = (unsigned short*)(ws + OFF_PROJL);
  _Float16*       vct   = (_Float16*)(ws + OFF_VCT);
  _Float16*       sg    = (_Float16*)(ws + OFF_SG);
  _Float16*       lg    = (_Float16*)(ws + OFF_LG);
  _Float16*       t1d   = (_Float16*)(ws + OFF_T1D);
  unsigned short* Phb   = (unsigned short*)(ws + OFF_PH);
  unsigned short* Plb   = (unsigned short*)(ws + OFF_PL);
  _Float16*       vuth  = (_Float16*)(ws + OFF_VUTH);
  _Float16*       vutl  = (_Float16*)(ws + OFF_VUTL);
  unsigned short* xh    = (unsigned short*)(ws + OFF_XH);
  unsigned short* xl    = (unsigned short*)(ws + OFF_XL);
  float*          Wb    = (float*)(ws + OFF_W);

  k_prep  <<<dim3(5632),   256, 0, stream>>>((const float*)d_in[1], (const float*)d_in[2],
                                             (const float*)d_in[3], (const float*)d_in[4],
                                             (const float*)d_in[5], (const float*)d_in[6],
                                             x, wth, wtl, xh, xl);
  k_proj  <<<dim3(384),    256, 0, stream>>>(xh, xl, wth, wtl, projh, projl, vct, vuth, vutl);
  k_p2    <<<dim3(152,4),  256, 0, stream>>>(projh, projl, vuth, vutl, sg, t1d, Wb);
  k_scan  <<<dim3(64,4),   256, 0, stream>>>(Wb, Phb, Plb);
  k_p3    <<<dim3(136,4),  256, 0, stream>>>(projh, projl, t1d, sg, Phb, Plb, lg);
  k_p4    <<<dim3(64,4),   256, 0, stream>>>(lg, vct, (float*)d_out);
}